// Round 1
// baseline (834.049 us; speedup 1.0000x reference)
//
#include <hip/hip_runtime.h>

typedef __attribute__((ext_vector_type(4))) float f32x4;
typedef __attribute__((ext_vector_type(8))) short bf16x8;   // 8 bf16 = 4 VGPRs (MFMA A/B frag)
typedef __attribute__((ext_vector_type(8))) unsigned short us8;
typedef __attribute__((ext_vector_type(4))) unsigned short us4;
typedef __attribute__((ext_vector_type(4))) float fl4;

static __device__ __forceinline__ unsigned short f2bf(float f) {
  union { float f; unsigned int u; } v; v.f = f;
  unsigned int u = v.u;
  return (unsigned short)((u + 0x7FFFu + ((u >> 16) & 1u)) >> 16);  // RNE
}

#define MFMA16(a, b, c) __builtin_amdgcn_mfma_f32_16x16x32_bf16((a), (b), (c), 0, 0, 0)

// ---------------- elementwise convert x: fp32 -> bf16 ----------------
__global__ __launch_bounds__(256) void convert_x(const float* __restrict__ in,
                                                 unsigned short* __restrict__ out, int n) {
  int i = (blockIdx.x * 256 + threadIdx.x) * 4;
  if (i >= n) return;
  fl4 v = *(const fl4*)&in[i];
  us4 o;
  o[0] = f2bf(v[0]); o[1] = f2bf(v[1]); o[2] = f2bf(v[2]); o[3] = f2bf(v[3]);
  *(us4*)&out[i] = o;
}

// ---------------- transpose+convert: fp32 [R][C] -> bf16 [C][R] ----------------
__global__ __launch_bounds__(256) void transpose_w(const float* __restrict__ in,
                                                   unsigned short* __restrict__ out,
                                                   int R, int C) {
  __shared__ float t[32][33];
  int bc = blockIdx.x * 32;  // C index
  int br = blockIdx.y * 32;  // R index
  int tx = threadIdx.x & 31, ty = threadIdx.x >> 5;
#pragma unroll
  for (int i = 0; i < 32; i += 8)
    t[ty + i][tx] = in[(br + ty + i) * C + bc + tx];
  __syncthreads();
#pragma unroll
  for (int i = 0; i < 32; i += 8)
    out[(bc + ty + i) * R + br + tx] = f2bf(t[tx][ty + i]);
}

// ---------------- transpose V: bf16 [bh][2048][64] -> [bh][64][2048] ----------------
__global__ __launch_bounds__(256) void transpose_v(const unsigned short* __restrict__ V,
                                                   unsigned short* __restrict__ Vt) {
  __shared__ unsigned short t[64][65];
  int bh = blockIdx.y;
  int q0 = blockIdx.x * 64;
  int tid = threadIdx.x;
#pragma unroll
  for (int i = 0; i < 16; i++) {
    int idx = tid + i * 256;
    int r = idx >> 6, c = idx & 63;
    t[r][c] = V[((size_t)bh * 2048 + q0 + r) * 64 + c];
  }
  __syncthreads();
#pragma unroll
  for (int i = 0; i < 16; i++) {
    int idx = tid + i * 256;
    int d = idx >> 6, q = idx & 63;
    Vt[((size_t)bh * 64 + d) * 2048 + q0 + q] = t[q][d];
  }
}

// ---------------- GEMM1: Xbf[4096,1024] @ WqkvT(B^T)[3072,1024] -> Q/K/V [bh][2048][64] bf16 ----------------
__global__ __launch_bounds__(256) void gemm_qkv(const unsigned short* __restrict__ X,
                                                const unsigned short* __restrict__ Bt,
                                                unsigned short* __restrict__ Qw,
                                                unsigned short* __restrict__ Kw,
                                                unsigned short* __restrict__ Vw) {
  __shared__ unsigned short As[128 * 32];
  __shared__ unsigned short Bs[128 * 32];
  const int tid = threadIdx.x;
  const int wave = tid >> 6, lane = tid & 63;
  const int quad = lane >> 4, ln = lane & 15;
  const int m0 = blockIdx.x * 128, n0 = blockIdx.y * 128;
  const int wr = (wave >> 1) * 64, wc = (wave & 1) * 64;
  const int srow = tid >> 2, soff = (tid & 3) << 3;
  f32x4 acc[4][4] = {};
  const unsigned short* Ag = X + (m0 + srow) * 1024 + soff;
  const unsigned short* Bg = Bt + (n0 + srow) * 1024 + soff;
  for (int k0 = 0; k0 < 1024; k0 += 32) {
    us8 a0 = *(const us8*)(Ag + k0);
    us8 a1 = *(const us8*)(Ag + 64 * 1024 + k0);
    us8 b0 = *(const us8*)(Bg + k0);
    us8 b1 = *(const us8*)(Bg + 64 * 1024 + k0);
    __syncthreads();
    *(us8*)&As[srow * 32 + soff] = a0;
    *(us8*)&As[(srow + 64) * 32 + soff] = a1;
    *(us8*)&Bs[srow * 32 + soff] = b0;
    *(us8*)&Bs[(srow + 64) * 32 + soff] = b1;
    __syncthreads();
    bf16x8 af[4], bfr[4];
#pragma unroll
    for (int i = 0; i < 4; i++) af[i] = *(const bf16x8*)&As[(wr + i * 16 + ln) * 32 + quad * 8];
#pragma unroll
    for (int j = 0; j < 4; j++) bfr[j] = *(const bf16x8*)&Bs[(wc + j * 16 + ln) * 32 + quad * 8];
#pragma unroll
    for (int i = 0; i < 4; i++)
#pragma unroll
      for (int j = 0; j < 4; j++)
        acc[i][j] = MFMA16(af[i], bfr[j], acc[i][j]);
  }
  // epilogue: scatter to Q/K/V in [b*16+h][q][d] bf16
#pragma unroll
  for (int j = 0; j < 4; j++) {
    int col = n0 + wc + j * 16 + ln;   // [0,3072)
    int part = col >> 10;              // 0=Q 1=K 2=V (uniform across 16 cols)
    int h = (col >> 6) & 15;
    int d = col & 63;
    unsigned short* dst = (part == 0) ? Qw : ((part == 1) ? Kw : Vw);
#pragma unroll
    for (int i = 0; i < 4; i++)
#pragma unroll
      for (int r = 0; r < 4; r++) {
        int row = m0 + wr + i * 16 + quad * 4 + r;  // token = b*2048+q
        int idx = ((((row >> 11) << 4) + h) * 2048 + (row & 2047)) * 64 + d;
        dst[idx] = f2bf(acc[i][j][r]);
      }
  }
}

// ---------------- fused attention ----------------
// block: (q-block of 64 rows) x (bh); 4 waves, each owns 16 q rows.
__global__ __launch_bounds__(256) void attn_fused(const unsigned short* __restrict__ Qw,
                                                  const unsigned short* __restrict__ Kw,
                                                  const unsigned short* __restrict__ Vt,
                                                  const float* __restrict__ mask,
                                                  float* __restrict__ attn,
                                                  unsigned short* __restrict__ AO) {
  __shared__ unsigned short Qs[64 * 64];
  __shared__ unsigned short Ks[64 * 64];
  __shared__ unsigned short Vs[64 * 64];
  __shared__ unsigned short Ps[4][16 * 64];
  __shared__ float mQ[64];
  __shared__ float mK[64];
  const int tid = threadIdx.x;
  const int wave = tid >> 6, lane = tid & 63;
  const int quad = lane >> 4, ln = lane & 15;
  const int bh = blockIdx.y, b = bh >> 4, h = bh & 15;
  const int q0 = blockIdx.x * 64;
  const float scale = 0.03125f;  // 1/sqrt(1024)
  const int c0 = tid, r0 = c0 >> 3, o0 = (c0 & 7) << 3;
  const int c1 = tid + 256, r1 = c1 >> 3, o1 = (c1 & 7) << 3;
  const unsigned short* Qg = Qw + (size_t)bh * 2048 * 64;
  const unsigned short* Kg = Kw + (size_t)bh * 2048 * 64;
  const unsigned short* Vg = Vt + (size_t)bh * 64 * 2048;

  *(us8*)&Qs[r0 * 64 + o0] = *(const us8*)&Qg[(q0 + r0) * 64 + o0];
  *(us8*)&Qs[r1 * 64 + o1] = *(const us8*)&Qg[(q0 + r1) * 64 + o1];
  if (tid < 64) mQ[tid] = mask[b * 2048 + q0 + tid];
  __syncthreads();

  const int qrb = wave * 16 + quad * 4;
  float mq[4];
#pragma unroll
  for (int r = 0; r < 4; r++) mq[r] = mQ[qrb + r];
  const bf16x8 aq0 = *(const bf16x8*)&Qs[(wave * 16 + ln) * 64 + quad * 8];
  const bf16x8 aq1 = *(const bf16x8*)&Qs[(wave * 16 + ln) * 64 + 32 + quad * 8];

  float mrun[4], lrun[4];
#pragma unroll
  for (int r = 0; r < 4; r++) { mrun[r] = -3.0e38f; lrun[r] = 0.0f; }

  // ---- pass 1: row max + denominator (online) ----
  for (int kt = 0; kt < 32; kt++) {
    const int k0 = kt * 64;
    us8 ka = *(const us8*)&Kg[(k0 + r0) * 64 + o0];
    us8 kb = *(const us8*)&Kg[(k0 + r1) * 64 + o1];
    float mkv = 0.0f;
    if (tid < 64) mkv = mask[b * 2048 + k0 + tid];
    __syncthreads();
    *(us8*)&Ks[r0 * 64 + o0] = ka;
    *(us8*)&Ks[r1 * 64 + o1] = kb;
    if (tid < 64) mK[tid] = mkv;
    __syncthreads();
    f32x4 s[4] = {};
#pragma unroll
    for (int nt = 0; nt < 4; nt++) {
      bf16x8 kb0 = *(const bf16x8*)&Ks[(nt * 16 + ln) * 64 + quad * 8];
      bf16x8 kb1 = *(const bf16x8*)&Ks[(nt * 16 + ln) * 64 + 32 + quad * 8];
      s[nt] = MFMA16(aq0, kb0, s[nt]);
      s[nt] = MFMA16(aq1, kb1, s[nt]);
    }
    float mkl[4];
#pragma unroll
    for (int nt = 0; nt < 4; nt++) mkl[nt] = mK[nt * 16 + ln];
    float lg[4][4], lmax[4];
#pragma unroll
    for (int r = 0; r < 4; r++) lmax[r] = -3.0e38f;
#pragma unroll
    for (int nt = 0; nt < 4; nt++)
#pragma unroll
      for (int r = 0; r < 4; r++) {
        float lgv = (mq[r] * mkl[nt] == 0.0f) ? -3125.0f : s[nt][r] * scale;
        lg[nt][r] = lgv;
        lmax[r] = fmaxf(lmax[r], lgv);
      }
#pragma unroll
    for (int off = 1; off < 16; off <<= 1)
#pragma unroll
      for (int r = 0; r < 4; r++) lmax[r] = fmaxf(lmax[r], __shfl_xor(lmax[r], off, 64));
    float ps[4] = {0.0f, 0.0f, 0.0f, 0.0f};
#pragma unroll
    for (int r = 0; r < 4; r++) {
      float mnew = fmaxf(mrun[r], lmax[r]);
      lrun[r] *= __expf(mrun[r] - mnew);
      mrun[r] = mnew;
    }
#pragma unroll
    for (int nt = 0; nt < 4; nt++)
#pragma unroll
      for (int r = 0; r < 4; r++) ps[r] += __expf(lg[nt][r] - mrun[r]);
#pragma unroll
    for (int off = 1; off < 16; off <<= 1)
#pragma unroll
      for (int r = 0; r < 4; r++) ps[r] += __shfl_xor(ps[r], off, 64);
#pragma unroll
    for (int r = 0; r < 4; r++) lrun[r] += ps[r];
  }

  float invl[4];
#pragma unroll
  for (int r = 0; r < 4; r++) invl[r] = 1.0f / lrun[r];
  float* arow[4];
#pragma unroll
  for (int r = 0; r < 4; r++) arow[r] = attn + ((size_t)bh * 2048 + (q0 + qrb + r)) * 2048;

  // ---- pass 2: recompute S, write normalized attn, accumulate O = P V ----
  f32x4 o[4] = {};
  for (int kt = 0; kt < 32; kt++) {
    const int k0 = kt * 64;
    us8 ka = *(const us8*)&Kg[(k0 + r0) * 64 + o0];
    us8 kb = *(const us8*)&Kg[(k0 + r1) * 64 + o1];
    us8 va = *(const us8*)&Vg[r0 * 2048 + k0 + o0];
    us8 vb = *(const us8*)&Vg[r1 * 2048 + k0 + o1];
    float mkv = 0.0f;
    if (tid < 64) mkv = mask[b * 2048 + k0 + tid];
    __syncthreads();
    *(us8*)&Ks[r0 * 64 + o0] = ka;
    *(us8*)&Ks[r1 * 64 + o1] = kb;
    *(us8*)&Vs[r0 * 64 + o0] = va;
    *(us8*)&Vs[r1 * 64 + o1] = vb;
    if (tid < 64) mK[tid] = mkv;
    __syncthreads();
    f32x4 s[4] = {};
#pragma unroll
    for (int nt = 0; nt < 4; nt++) {
      bf16x8 kb0 = *(const bf16x8*)&Ks[(nt * 16 + ln) * 64 + quad * 8];
      bf16x8 kb1 = *(const bf16x8*)&Ks[(nt * 16 + ln) * 64 + 32 + quad * 8];
      s[nt] = MFMA16(aq0, kb0, s[nt]);
      s[nt] = MFMA16(aq1, kb1, s[nt]);
    }
    float mkl[4];
#pragma unroll
    for (int nt = 0; nt < 4; nt++) mkl[nt] = mK[nt * 16 + ln];
#pragma unroll
    for (int nt = 0; nt < 4; nt++)
#pragma unroll
      for (int r = 0; r < 4; r++) {
        float lgv = (mq[r] * mkl[nt] == 0.0f) ? -3125.0f : s[nt][r] * scale;
        float p = __expf(lgv - mrun[r]) * invl[r];
        arow[r][k0 + nt * 16 + ln] = p;                        // fp32 attn out (the 537MB)
        Ps[wave][(quad * 4 + r) * 64 + nt * 16 + ln] = f2bf(p);  // C-layout -> LDS
      }
    // LDS round-trip: read P back in A-operand layout (same-wave DS ops are in-order)
    bf16x8 pa0 = *(const bf16x8*)&Ps[wave][ln * 64 + quad * 8];
    bf16x8 pa1 = *(const bf16x8*)&Ps[wave][ln * 64 + 32 + quad * 8];
#pragma unroll
    for (int nt = 0; nt < 4; nt++) {
      bf16x8 vb0 = *(const bf16x8*)&Vs[(nt * 16 + ln) * 64 + quad * 8];
      bf16x8 vb1 = *(const bf16x8*)&Vs[(nt * 16 + ln) * 64 + 32 + quad * 8];
      o[nt] = MFMA16(pa0, vb0, o[nt]);
      o[nt] = MFMA16(pa1, vb1, o[nt]);
    }
  }
  // epilogue: attn_out bf16 [token][1024]
#pragma unroll
  for (int nt = 0; nt < 4; nt++)
#pragma unroll
    for (int r = 0; r < 4; r++) {
      int token = b * 2048 + q0 + qrb + r;
      AO[(size_t)token * 1024 + h * 64 + nt * 16 + ln] = f2bf(o[nt][r]);
    }
}

// ---------------- GEMM3: AO[4096,1024] @ WhT(B^T)[1024,1024] + b -> out fp32 ----------------
__global__ __launch_bounds__(256) void gemm_out(const unsigned short* __restrict__ A,
                                                const unsigned short* __restrict__ Bt,
                                                const float* __restrict__ bias,
                                                float* __restrict__ out) {
  __shared__ unsigned short As[128 * 32];
  __shared__ unsigned short Bs[128 * 32];
  const int tid = threadIdx.x;
  const int wave = tid >> 6, lane = tid & 63;
  const int quad = lane >> 4, ln = lane & 15;
  const int m0 = blockIdx.x * 128, n0 = blockIdx.y * 128;
  const int wr = (wave >> 1) * 64, wc = (wave & 1) * 64;
  const int srow = tid >> 2, soff = (tid & 3) << 3;
  f32x4 acc[4][4] = {};
  const unsigned short* Ag = A + (m0 + srow) * 1024 + soff;
  const unsigned short* Bg = Bt + (n0 + srow) * 1024 + soff;
  for (int k0 = 0; k0 < 1024; k0 += 32) {
    us8 a0 = *(const us8*)(Ag + k0);
    us8 a1 = *(const us8*)(Ag + 64 * 1024 + k0);
    us8 b0 = *(const us8*)(Bg + k0);
    us8 b1 = *(const us8*)(Bg + 64 * 1024 + k0);
    __syncthreads();
    *(us8*)&As[srow * 32 + soff] = a0;
    *(us8*)&As[(srow + 64) * 32 + soff] = a1;
    *(us8*)&Bs[srow * 32 + soff] = b0;
    *(us8*)&Bs[(srow + 64) * 32 + soff] = b1;
    __syncthreads();
    bf16x8 af[4], bfr[4];
#pragma unroll
    for (int i = 0; i < 4; i++) af[i] = *(const bf16x8*)&As[(wr + i * 16 + ln) * 32 + quad * 8];
#pragma unroll
    for (int j = 0; j < 4; j++) bfr[j] = *(const bf16x8*)&Bs[(wc + j * 16 + ln) * 32 + quad * 8];
#pragma unroll
    for (int i = 0; i < 4; i++)
#pragma unroll
      for (int j = 0; j < 4; j++)
        acc[i][j] = MFMA16(af[i], bfr[j], acc[i][j]);
  }
#pragma unroll
  for (int j = 0; j < 4; j++) {
    int col = n0 + wc + j * 16 + ln;
    float bv = bias[col];
#pragma unroll
    for (int i = 0; i < 4; i++)
#pragma unroll
      for (int r = 0; r < 4; r++) {
        int row = m0 + wr + i * 16 + quad * 4 + r;
        out[(size_t)row * 1024 + col] = acc[i][j][r] + bv;
      }
  }
}

extern "C" void kernel_launch(void* const* d_in, const int* in_sizes, int n_in,
                              void* d_out, int out_size, void* d_ws, size_t ws_size,
                              hipStream_t stream) {
  const float* x = (const float*)d_in[0];      // [2,2048,1024]
  const float* mask = (const float*)d_in[1];   // [2,2048]
  const float* Wqkv = (const float*)d_in[2];   // [1024,3072]
  const float* Wh = (const float*)d_in[3];     // [1024,1024]
  const float* bh = (const float*)d_in[4];     // [1024]
  float* out = (float*)d_out;                  // [2,2048,1024]
  float* attn = out + 4194304;                 // [2,16,2048,2048]

  unsigned short* ws = (unsigned short*)d_ws;
  unsigned short* Xbf   = ws;                  // 4194304
  unsigned short* WqkvT = ws + 4194304;        // 3145728  [3072][1024]
  unsigned short* WhT   = ws + 7340032;        // 1048576  [1024][1024]
  unsigned short* Qw    = ws + 8388608;        // 4194304  [bh][2048][64]
  unsigned short* Kw    = ws + 12582912;       // 4194304
  unsigned short* Vw    = ws + 16777216;       // 4194304
  unsigned short* Vtw   = ws + 20971520;       // 4194304  [bh][64][2048]
  unsigned short* AO    = ws + 25165824;       // 4194304  [4096][1024]

  convert_x<<<dim3(4096), dim3(256), 0, stream>>>(x, Xbf, 4194304);
  transpose_w<<<dim3(96, 32), dim3(256), 0, stream>>>(Wqkv, WqkvT, 1024, 3072);
  transpose_w<<<dim3(32, 32), dim3(256), 0, stream>>>(Wh, WhT, 1024, 1024);
  gemm_qkv<<<dim3(32, 24), dim3(256), 0, stream>>>(Xbf, WqkvT, Qw, Kw, Vw);
  transpose_v<<<dim3(32, 32), dim3(256), 0, stream>>>(Vw, Vtw);
  attn_fused<<<dim3(32, 32), dim3(256), 0, stream>>>(Qw, Kw, Vtw, mask, attn, AO);
  gemm_out<<<dim3(32, 8), dim3(256), 0, stream>>>(AO, WhT, bh, out);
}